// Round 1
// baseline (10187.881 us; speedup 1.0000x reference)
//
#include <hip/hip_runtime.h>
#include <cmath>

#ifndef M_PI
#define M_PI 3.14159265358979323846
#endif

#define K_CHEB 48
#define A_CHEB 0.05
#define B_CHEB 14.0

struct ChebCoef {
  float mid, invhalf;
  float c[K_CHEB + 1];
};

// ---------- helpers ----------

__device__ __forceinline__ void stage64(const float* __restrict__ g, float* __restrict__ s, int tid) {
#pragma unroll
  for (int r = 0; r < 4; r++) {
    int idx = tid + 256 * r;                       // float4 index, 1024 per matrix
    *(float4*)(s + 4 * idx) = *(const float4*)(g + 4 * idx);
  }
}

__device__ __forceinline__ void store_tile(float* __restrict__ S, int r0, int c0, const float t[16]) {
#pragma unroll
  for (int i = 0; i < 4; i++)
    *(float4*)(S + (r0 + i) * 64 + c0) = *(const float4*)(&t[4 * i]);
}

// C[r0+i][c0+j] = sum_k A[k][r0+i] * B[k][c0+j]  == (A^T B).
// Equals A*B when A is symmetric (or when A holds the transpose you want).
// Row-wise float4 LDS reads for both operands -> aligned b128, conflict-free.
__device__ __forceinline__ void gemm_tile_sym(const float* __restrict__ A, const float* __restrict__ B,
                                              int r0, int c0, float t[16]) {
#pragma unroll
  for (int i = 0; i < 16; i++) t[i] = 0.f;
#pragma unroll 4
  for (int k = 0; k < 64; k += 4) {
    float a[16], b[16];
#pragma unroll
    for (int kk = 0; kk < 4; kk++) {
      *(float4*)(&a[4 * kk]) = *(const float4*)(A + (k + kk) * 64 + r0);
      *(float4*)(&b[4 * kk]) = *(const float4*)(B + (k + kk) * 64 + c0);
    }
#pragma unroll
    for (int kk = 0; kk < 4; kk++)
#pragma unroll
      for (int i = 0; i < 4; i++)
#pragma unroll
        for (int j = 0; j < 4; j++)
          t[4 * i + j] += a[4 * kk + i] * b[4 * kk + j];
  }
}

// ---------- stage 1: batch mean (partial over groups of 8) ----------

__global__ __launch_bounds__(256) void reduce_mean8(const float* __restrict__ data,
                                                    float* __restrict__ part) {
  const size_t base = (size_t)blockIdx.x * 8 * 4096;
  const int tid = threadIdx.x;
#pragma unroll
  for (int r = 0; r < 4; r++) {
    int idx = tid + 256 * r;
    float4 s = make_float4(0.f, 0.f, 0.f, 0.f);
#pragma unroll
    for (int m = 0; m < 8; m++) {
      float4 v = *(const float4*)(data + base + (size_t)m * 4096 + 4 * idx);
      s.x += v.x; s.y += v.y; s.z += v.z; s.w += v.w;
    }
    *(float4*)(part + (size_t)blockIdx.x * 4096 + 4 * idx) = s;
  }
}

__global__ __launch_bounds__(256) void reduce_cols(const float* __restrict__ part,
                                                   float* __restrict__ outv,
                                                   int nparts, float scale) {
  const int j = blockIdx.x * 256 + threadIdx.x;   // 16 blocks -> 4096
  float s = 0.f;
  for (int g = 0; g < nparts; g++) s += part[(size_t)g * 4096 + j];
  outv[j] = s * scale;
}

// ---------- per-batch Chebyshev logm accumulation (the hot kernel) ----------

__global__ __launch_bounds__(256, 2) void cheb_accum(const float* __restrict__ data,
                                                     const float* __restrict__ Mi,
                                                     float* __restrict__ partial,
                                                     ChebCoef cc) {
  __shared__ float sMi[4096], sW[4096], sPa[4096], sPb[4096];   // 64 KB -> 2 blocks/CU
  const int tid = threadIdx.x;
  const int r0 = (tid >> 4) << 2, c0 = (tid & 15) << 2;
  float accT[16];
#pragma unroll
  for (int i = 0; i < 16; i++) accT[i] = 0.f;

  stage64(Mi, sMi, tid);
  __syncthreads();
  float t[16];

#pragma unroll 1
  for (int m = 0; m < 8; m++) {
    const float* D = data + ((size_t)blockIdx.x * 8 + m) * 4096;
    stage64(D, sPa, tid);
    __syncthreads();

    gemm_tile_sym(sPa, sMi, r0, c0, t);          // tmp = D * Mi  (D symmetric)
    store_tile(sPb, r0, c0, t);
    __syncthreads();

    gemm_tile_sym(sMi, sPb, r0, c0, t);          // W = Mi * tmp  (Mi symmetric)
#pragma unroll
    for (int i = 0; i < 4; i++)
#pragma unroll
      for (int j = 0; j < 4; j++) {
        float d = ((r0 + i) == (c0 + j)) ? 1.f : 0.f;
        float w = (t[4 * i + j] - cc.mid * d) * cc.invhalf;   // What = (W - mid I)/half
        sW[(r0 + i) * 64 + (c0 + j)] = w;
        accT[4 * i + j] += cc.c[0] * d + cc.c[1] * w;
      }
    __syncthreads();

    // k = 2 : P2 = 2*What^2 - I
    gemm_tile_sym(sW, sW, r0, c0, t);
#pragma unroll
    for (int i = 0; i < 4; i++)
#pragma unroll
      for (int j = 0; j < 4; j++) {
        float d = ((r0 + i) == (c0 + j)) ? 1.f : 0.f;
        float v = 2.f * t[4 * i + j] - d;
        sPa[(r0 + i) * 64 + (c0 + j)] = v;
        accT[4 * i + j] += cc.c[2] * v;
      }
    __syncthreads();

    // k = 3 : P3 = 2*What*P2 - What
    gemm_tile_sym(sW, sPa, r0, c0, t);
#pragma unroll
    for (int i = 0; i < 4; i++)
#pragma unroll
      for (int j = 0; j < 4; j++) {
        float v = 2.f * t[4 * i + j] - sW[(r0 + i) * 64 + (c0 + j)];
        sPb[(r0 + i) * 64 + (c0 + j)] = v;
        accT[4 * i + j] += cc.c[3] * v;
      }
    __syncthreads();

    float* cur = sPb;
    float* prev = sPa;
#pragma unroll 1
    for (int k = 4; k <= K_CHEB; k++) {
      gemm_tile_sym(sW, cur, r0, c0, t);
      const float ck = cc.c[k];
#pragma unroll
      for (int i = 0; i < 4; i++)
#pragma unroll
        for (int j = 0; j < 4; j++) {
          int off = (r0 + i) * 64 + (c0 + j);
          float v = 2.f * t[4 * i + j] - prev[off];   // only owner touches (i,j) of prev
          prev[off] = v;
          accT[4 * i + j] += ck * v;
        }
      __syncthreads();
      float* tp = cur; cur = prev; prev = tp;
    }
  }

  float* pp = partial + (size_t)blockIdx.x * 4096;
#pragma unroll
  for (int i = 0; i < 4; i++)
    *(float4*)(pp + (r0 + i) * 64 + c0) = *(const float4*)(&accT[4 * i]);
}

// ---------- single-matrix sqrt / invsqrt via binomial series (M ~ c*(I+E), ||E|| small) ----------

__global__ __launch_bounds__(256) void invsqrt_series(const float* __restrict__ Min,
                                                      float* __restrict__ MiOut,
                                                      float* __restrict__ MsOut) {
  __shared__ float sM[4096], sE[4096], sE2[4096], sE3[4096];
  __shared__ float csh;
  const int tid = threadIdx.x;
  const int r0 = (tid >> 4) << 2, c0 = (tid & 15) << 2;

  stage64(Min, sM, tid);
  __syncthreads();
  if (tid == 0) {
    float s = 0.f;
    for (int i = 0; i < 64; i++) s += sM[i * 64 + i];
    csh = s * (1.f / 64.f);
  }
  __syncthreads();
  const float invc = 1.f / csh;
  for (int idx = tid; idx < 4096; idx += 256) {
    int r = idx >> 6, c = idx & 63;
    sE[idx] = 0.5f * (sM[idx] + sM[c * 64 + r]) * invc - ((r == c) ? 1.f : 0.f);  // sym + normalize
  }
  __syncthreads();

  float t[16];
  gemm_tile_sym(sE, sE, r0, c0, t);  store_tile(sE2, r0, c0, t); __syncthreads();  // E^2
  gemm_tile_sym(sE2, sE, r0, c0, t); store_tile(sE3, r0, c0, t); __syncthreads();  // E^3
  gemm_tile_sym(sE2, sE2, r0, c0, t); store_tile(sM, r0, c0, t); __syncthreads();  // E^4 (reuse sM)
  float t5[16];
  gemm_tile_sym(sE2, sE3, r0, c0, t5);                                             // E^5 (regs)

  const float sc = sqrtf(csh), rsc = 1.f / sc;
#pragma unroll
  for (int i = 0; i < 4; i++)
#pragma unroll
    for (int j = 0; j < 4; j++) {
      int off = (r0 + i) * 64 + (c0 + j);
      float d = ((r0 + i) == (c0 + j)) ? 1.f : 0.f;
      float e = sE[off], e2 = sE2[off], e3 = sE3[off], e4 = sM[off], e5 = t5[4 * i + j];
      // (1+x)^(-1/2), (1+x)^(1/2) to x^5
      float mi = (d - 0.5f * e + 0.375f * e2 - 0.3125f * e3 + 0.2734375f * e4 - 0.24609375f * e5) * rsc;
      float ms = (d + 0.5f * e - 0.125f * e2 + 0.0625f * e3 - 0.0390625f * e4 + 0.02734375f * e5) * sc;
      MiOut[off] = mi;
      MsOut[off] = ms;
    }
}

// ---------- Taylor-8 expm (Horner), A symmetric, result *= postscale ----------

__device__ void taylor_expm8(const float* __restrict__ sA, float* __restrict__ sR,
                             int tid, int r0, int c0, float postscale) {
  for (int idx = tid; idx < 4096; idx += 256) {
    int r = idx >> 6, c = idx & 63;
    sR[idx] = ((r == c) ? 1.f : 0.f) + sA[idx] * 0.125f;   // I + A/8
  }
  __syncthreads();
  float t[16];
#pragma unroll 1
  for (int k = 7; k >= 1; k--) {
    gemm_tile_sym(sA, sR, r0, c0, t);
    __syncthreads();
    const float inv = 1.f / (float)k;
    const float fin = (k == 1) ? postscale : 1.f;
#pragma unroll
    for (int i = 0; i < 4; i++)
#pragma unroll
      for (int j = 0; j < 4; j++) {
        int off = (r0 + i) * 64 + (c0 + j);
        float d = ((r0 + i) == (c0 + j)) ? 1.f : 0.f;
        sR[off] = (d + t[4 * i + j] * inv) * fin;
      }
    __syncthreads();
  }
}

// ---------- M <- Ms * expm(T) * Ms ----------

__global__ __launch_bounds__(256) void expm_update(const float* __restrict__ Tin,
                                                   const float* __restrict__ Msin,
                                                   float* __restrict__ Mout) {
  __shared__ float sA[4096], sR[4096], sB[4096];
  __shared__ float mush;
  const int tid = threadIdx.x;
  const int r0 = (tid >> 4) << 2, c0 = (tid & 15) << 2;

  stage64(Tin, sB, tid);
  __syncthreads();
  if (tid == 0) {
    float s = 0.f;
    for (int i = 0; i < 64; i++) s += sB[i * 64 + i];
    mush = s * (1.f / 64.f);
  }
  __syncthreads();
  const float mu = mush;
  for (int idx = tid; idx < 4096; idx += 256) {
    int r = idx >> 6, c = idx & 63;
    sA[idx] = 0.5f * (sB[idx] + sB[c * 64 + r]) - ((r == c) ? mu : 0.f);  // sym(T) - mu I
  }
  __syncthreads();
  taylor_expm8(sA, sR, tid, r0, c0, expf(mu));       // sR = expm(T)

  stage64(Msin, sB, tid);
  __syncthreads();
  float t[16];
  gemm_tile_sym(sR, sB, r0, c0, t);                  // tmp = R * Ms   (R sym)
  store_tile(sA, r0, c0, t);
  __syncthreads();
  gemm_tile_sym(sB, sA, r0, c0, t);                  // M = Ms * tmp   (Ms sym)
#pragma unroll
  for (int i = 0; i < 4; i++)
    *(float4*)(Mout + (r0 + i) * 64 + c0) = *(const float4*)(&t[4 * i]);
}

// ---------- S = expm(sym(bias)/2), P = S*G ----------

__global__ __launch_bounds__(256) void bias_expm_P(const float* __restrict__ bias,
                                                   const float* __restrict__ Gin,
                                                   float* __restrict__ Pout) {
  __shared__ float sA[4096], sR[4096], sB[4096];
  const int tid = threadIdx.x;
  const int r0 = (tid >> 4) << 2, c0 = (tid & 15) << 2;

  stage64(bias, sB, tid);
  __syncthreads();
  for (int idx = tid; idx < 4096; idx += 256) {
    int r = idx >> 6, c = idx & 63;
    sA[idx] = 0.0625f * (sB[idx] + sB[c * 64 + r]);  // sym(bias)/2 / 4  (2 squarings later)
  }
  __syncthreads();
  taylor_expm8(sA, sR, tid, r0, c0, 1.f);            // R = expm(arg/4)

  float t[16];
  gemm_tile_sym(sR, sR, r0, c0, t);                  // R^2
  store_tile(sB, r0, c0, t);
  __syncthreads();
  gemm_tile_sym(sB, sB, r0, c0, t);                  // S = R^4
  store_tile(sR, r0, c0, t);
  stage64(Gin, sA, tid);
  __syncthreads();
  gemm_tile_sym(sR, sA, r0, c0, t);                  // P = S * G   (S sym)
#pragma unroll
  for (int i = 0; i < 4; i++)
    *(float4*)(Pout + (r0 + i) * 64 + c0) = *(const float4*)(&t[4 * i]);
}

// ---------- out_b = P * data_b * P^T ----------

__global__ __launch_bounds__(256) void final_out(const float* __restrict__ data,
                                                 const float* __restrict__ Pin,
                                                 float* __restrict__ out) {
  __shared__ float sPT[4096], sD[4096], sT[4096];
  const int tid = threadIdx.x;
  const int r0 = (tid >> 4) << 2, c0 = (tid & 15) << 2;

  for (int idx = tid; idx < 4096; idx += 256) {
    int r = idx >> 6, c = idx & 63;
    sPT[c * 64 + r] = Pin[idx];                      // P^T
  }
  __syncthreads();
  float t[16];
#pragma unroll 1
  for (int m = 0; m < 8; m++) {
    size_t b = (size_t)blockIdx.x * 8 + m;
    stage64(data + b * 4096, sD, tid);
    __syncthreads();
    gemm_tile_sym(sD, sPT, r0, c0, t);               // tmp = D * P^T  (D sym)
    store_tile(sT, r0, c0, t);
    __syncthreads();
    gemm_tile_sym(sPT, sT, r0, c0, t);               // out = P * tmp  (A-frag from P^T rows)
    float* ob = out + b * 4096;
#pragma unroll
    for (int i = 0; i < 4; i++)
      *(float4*)(ob + (r0 + i) * 64 + c0) = *(const float4*)(&t[4 * i]);
    __syncthreads();
  }
}

// ---------- launch ----------

extern "C" void kernel_launch(void* const* d_in, const int* in_sizes, int n_in,
                              void* d_out, int out_size, void* d_ws, size_t ws_size,
                              hipStream_t stream) {
  const float* data = (const float*)d_in[0];
  const float* bias = (const float*)d_in[1];
  float* out = (float*)d_out;

  // 16 MB partial-reduction scratch lives in d_out (written before read; final pass overwrites all).
  float* part = out;
  float* M  = (float*)d_ws;
  float* Mi = M + 4096;
  float* Ms = Mi + 4096;
  float* Tm = Ms + 4096;
  float* G  = Tm + 4096;
  float* P  = G + 4096;

  ChebCoef cc;
  {
    const double a = A_CHEB, b = B_CHEB;
    const int N = 256;
    double coef[K_CHEB + 1];
    for (int j = 0; j <= K_CHEB; j++) {
      double s = 0.0;
      for (int k = 0; k < N; k++) {
        double th = M_PI * (k + 0.5) / N;
        double x = 0.5 * (a + b) + 0.5 * (b - a) * std::cos(th);
        s += std::log(x) * std::cos(j * th);
      }
      coef[j] = 2.0 * s / N;
    }
    cc.mid = (float)(0.5 * (a + b));
    cc.invhalf = (float)(2.0 / (b - a));
    cc.c[0] = (float)(0.5 * coef[0]);
    for (int j = 1; j <= K_CHEB; j++) cc.c[j] = (float)coef[j];
  }

  reduce_mean8<<<1024, 256, 0, stream>>>(data, part);
  reduce_cols<<<16, 256, 0, stream>>>(part, M, 1024, 1.f / 8192.f);

  for (int it = 0; it < 3; ++it) {
    invsqrt_series<<<1, 256, 0, stream>>>(M, Mi, Ms);
    cheb_accum<<<1024, 256, 0, stream>>>(data, Mi, part, cc);
    reduce_cols<<<16, 256, 0, stream>>>(part, Tm, 1024, 1.f / 8192.f);
    expm_update<<<1, 256, 0, stream>>>(Tm, Ms, M);
  }

  invsqrt_series<<<1, 256, 0, stream>>>(M, G, Ms);   // G = invsqrtm(sym(M)); Ms = scratch
  bias_expm_P<<<1, 256, 0, stream>>>(bias, G, P);
  final_out<<<1024, 256, 0, stream>>>(data, P, out);
}

// Round 2
// 2871.556 us; speedup vs baseline: 3.5479x; 3.5479x over previous
//
#include <hip/hip_runtime.h>
#include <cmath>

#ifndef M_PI
#define M_PI 3.14159265358979323846
#endif

#define K_CHEB 48
#define A_CHEB 0.05
#define B_CHEB 14.0
#define PS_S 7
#define PS_Q 6

typedef __attribute__((ext_vector_type(8))) short bhalf8;
typedef __attribute__((ext_vector_type(16))) float f32x16;

struct PSArg {
  float mid, invhalf;
  float a[PS_Q + 1][PS_S];   // a[q][r]
};

// ---------- bf16 split helpers ----------

__device__ __forceinline__ short bf16_rne(float x) {
  unsigned u = __float_as_uint(x);
  return (short)((u + 0x7fffu + ((u >> 16) & 1u)) >> 16);
}
__device__ __forceinline__ float bf16_tof(short h) {
  return __uint_as_float(((unsigned)(unsigned short)h) << 16);
}
__device__ __forceinline__ void split1(float x, short& h, short& l) {
  h = bf16_rne(x);
  l = bf16_rne(x - bf16_tof(h));
}

// ---------- generic fp32 LDS helpers (small single-matrix kernels) ----------

__device__ __forceinline__ void stage64(const float* __restrict__ g, float* __restrict__ s, int tid) {
#pragma unroll
  for (int r = 0; r < 4; r++) {
    int idx = tid + 256 * r;
    *(float4*)(s + 4 * idx) = *(const float4*)(g + 4 * idx);
  }
}

__device__ __forceinline__ void store_tile(float* __restrict__ S, int r0, int c0, const float t[16]) {
#pragma unroll
  for (int i = 0; i < 4; i++)
    *(float4*)(S + (r0 + i) * 64 + c0) = *(const float4*)(&t[4 * i]);
}

// C = A^T B (== A*B for symmetric A). Row-wise float4 LDS reads.
__device__ __forceinline__ void gemm_tile_sym(const float* __restrict__ A, const float* __restrict__ B,
                                              int r0, int c0, float t[16]) {
#pragma unroll
  for (int i = 0; i < 16; i++) t[i] = 0.f;
#pragma unroll 4
  for (int k = 0; k < 64; k += 4) {
    float a[16], b[16];
#pragma unroll
    for (int kk = 0; kk < 4; kk++) {
      *(float4*)(&a[4 * kk]) = *(const float4*)(A + (k + kk) * 64 + r0);
      *(float4*)(&b[4 * kk]) = *(const float4*)(B + (k + kk) * 64 + c0);
    }
#pragma unroll
    for (int kk = 0; kk < 4; kk++)
#pragma unroll
      for (int i = 0; i < 4; i++)
#pragma unroll
        for (int j = 0; j < 4; j++)
          t[4 * i + j] += a[4 * kk + i] * b[4 * kk + j];
  }
}

// ---------- batch mean ----------

__global__ __launch_bounds__(256) void reduce_mean8(const float* __restrict__ data,
                                                    float* __restrict__ part) {
  const size_t base = (size_t)blockIdx.x * 8 * 4096;
  const int tid = threadIdx.x;
#pragma unroll
  for (int r = 0; r < 4; r++) {
    int idx = tid + 256 * r;
    float4 s = make_float4(0.f, 0.f, 0.f, 0.f);
#pragma unroll
    for (int m = 0; m < 8; m++) {
      float4 v = *(const float4*)(data + base + (size_t)m * 4096 + 4 * idx);
      s.x += v.x; s.y += v.y; s.z += v.z; s.w += v.w;
    }
    *(float4*)(part + (size_t)blockIdx.x * 4096 + 4 * idx) = s;
  }
}

__global__ __launch_bounds__(256) void reduce_cols(const float* __restrict__ part,
                                                   float* __restrict__ outv,
                                                   int nparts, float scale) {
  const int j = blockIdx.x * 256 + threadIdx.x;
  float s = 0.f;
  for (int g = 0; g < nparts; g++) s += part[(size_t)g * 4096 + j];
  outv[j] = s * scale;
}

// ---------- the hot kernel: per-batch logm via MFMA + Paterson-Stockmeyer ----------
//
// Per 64x64 matrix: W = Mi*D*Mi (2 products), T_r = 2*What*T_{r-1}-T_{r-2} r=2..7
// (6 products, T_1..T_6 kept element-wise in regs), then matrix-Clenshaw in
// Y = T_7 with matrix coefficients G_q = sum_r a[q][r] T_r (6 products).
// All products: fp32 split to bf16 hi/lo, 3 MFMA (hi*hi + hi*lo + lo*hi).
// B-operand is stored TRANSPOSED in LDS (exact, from D-layout regs) so B-frags
// are contiguous ds_read_b128; A-operand fragments live in registers.

#define LDX 72   // padded row stride (elements); 144 B = 9*16 B -> 16B-aligned frags

__device__ __forceinline__ void load_afrags(const short* __restrict__ Xh, const short* __restrict__ Xl,
                                            int aoff, bhalf8 ah[4], bhalf8 al[4]) {
#pragma unroll
  for (int kb = 0; kb < 4; kb++) {
    ah[kb] = *(const bhalf8*)(Xh + aoff + 16 * kb);
    al[kb] = *(const bhalf8*)(Xl + aoff + 16 * kb);
  }
}

__device__ __forceinline__ f32x16 prod3(const bhalf8 ah[4], const bhalf8 al[4],
                                        const short* __restrict__ Bh, const short* __restrict__ Bl,
                                        int boff) {
  f32x16 acc;
#pragma unroll
  for (int t = 0; t < 16; t++) acc[t] = 0.f;
#pragma unroll
  for (int kb = 0; kb < 4; kb++) {
    bhalf8 bh = *(const bhalf8*)(Bh + boff + 16 * kb);
    bhalf8 bl = *(const bhalf8*)(Bl + boff + 16 * kb);
    acc = __builtin_amdgcn_mfma_f32_32x32x16_bf16(ah[kb], bh, acc, 0, 0, 0);
    acc = __builtin_amdgcn_mfma_f32_32x32x16_bf16(ah[kb], bl, acc, 0, 0, 0);
    acc = __builtin_amdgcn_mfma_f32_32x32x16_bf16(al[kb], bh, acc, 0, 0, 0);
  }
  return acc;
}

// write v^T (hi/lo bf16) into X: X[n][m] = v[m][n]; n = bcol, m = 32R+8g+4*half+t
__device__ __forceinline__ void tstore16(short* __restrict__ Xh, short* __restrict__ Xl,
                                         int bcol, int R, int half, const f32x16 v) {
#pragma unroll
  for (int g = 0; g < 4; g++) {
    short4 h, l;
    split1(v[4 * g + 0], h.x, l.x);
    split1(v[4 * g + 1], h.y, l.y);
    split1(v[4 * g + 2], h.z, l.z);
    split1(v[4 * g + 3], h.w, l.w);
    int off = bcol * LDX + 32 * R + 8 * g + 4 * half;
    *(short4*)(Xh + off) = h;
    *(short4*)(Xl + off) = l;
  }
}

__global__ __launch_bounds__(256, 2) void cheb_ps(const float* __restrict__ data,
                                                  const float* __restrict__ Mi,
                                                  float* __restrict__ partial,
                                                  PSArg co) {
  __shared__ __align__(16) short sXh[64 * LDX], sXl[64 * LDX];
  __shared__ __align__(16) short sMh[64 * LDX], sMl[64 * LDX];

  const int tid = threadIdx.x;
  const int lane = tid & 63, wv = tid >> 6;
  const int R = wv >> 1, C = wv & 1;
  const int ln31 = lane & 31, half = lane >> 5;
  const int aoff = (32 * R + ln31) * LDX + half * 8;   // A-frag element offset (+16*kb)
  const int bcol = 32 * C + ln31;
  const int boff = bcol * LDX + half * 8;              // B-frag element offset (+16*kb)

  // diagonal indicator for this lane's 16 D-layout entries
  f32x16 dg;
#pragma unroll
  for (int g = 0; g < 4; g++)
#pragma unroll
    for (int t = 0; t < 4; t++)
      dg[4 * g + t] = ((32 * R + 8 * g + 4 * half + t) == bcol) ? 1.f : 0.f;

  // stage Mi (block-constant) as bf16 hi/lo, row-major
#pragma unroll
  for (int i = 0; i < 4; i++) {
    int idx = tid + 256 * i;            // float4 slot 0..1023
    float4 v = *(const float4*)(Mi + 4 * idx);
    int row = idx >> 4, col = (idx & 15) << 2;
    short4 h, l;
    split1(v.x, h.x, l.x); split1(v.y, h.y, l.y);
    split1(v.z, h.z, l.z); split1(v.w, h.w, l.w);
    *(short4*)(sMh + row * LDX + col) = h;
    *(short4*)(sMl + row * LDX + col) = l;
  }

  f32x16 accTm;
#pragma unroll
  for (int t = 0; t < 16; t++) accTm[t] = 0.f;

  bhalf8 ah[4], al[4];
  __syncthreads();

#pragma unroll 1
  for (int m = 0; m < 8; m++) {
    const float* D = data + ((size_t)blockIdx.x * 8 + m) * 4096;
    // stage D -> X row-major (D symmetric)
#pragma unroll
    for (int i = 0; i < 4; i++) {
      int idx = tid + 256 * i;
      float4 v = *(const float4*)(D + 4 * idx);
      int row = idx >> 4, col = (idx & 15) << 2;
      short4 h, l;
      split1(v.x, h.x, l.x); split1(v.y, h.y, l.y);
      split1(v.z, h.z, l.z); split1(v.w, h.w, l.w);
      *(short4*)(sXh + row * LDX + col) = h;
      *(short4*)(sXl + row * LDX + col) = l;
    }
    __syncthreads();

    // P1: V = D*Mi  (A=D from X, B=Mi symmetric from XM)
    load_afrags(sXh, sXl, aoff, ah, al);
    f32x16 acc = prod3(ah, al, sMh, sMl, boff);
    __syncthreads();
    tstore16(sXh, sXl, bcol, R, half, acc);          // X := V^T
    __syncthreads();

    // P2: W = Mi*V  (A=Mi, B=V via X=V^T)
    load_afrags(sMh, sMl, aoff, ah, al);
    acc = prod3(ah, al, sXh, sXl, boff);
    f32x16 T1;
#pragma unroll
    for (int t = 0; t < 16; t++) T1[t] = (acc[t] - co.mid * dg[t]) * co.invhalf;  // What
    __syncthreads();
    tstore16(sXh, sXl, bcol, R, half, T1);           // X := What^T
    __syncthreads();

    // A := What (read X row-major; == What^T, symmetric to ~1e-4 - washed out by sym() later)
    load_afrags(sXh, sXl, aoff, ah, al);

    f32x16 T2, T3, T4, T5, T6;
    // r=2
    acc = prod3(ah, al, sXh, sXl, boff);
#pragma unroll
    for (int t = 0; t < 16; t++) T2[t] = 2.f * acc[t] - dg[t];
    __syncthreads(); tstore16(sXh, sXl, bcol, R, half, T2); __syncthreads();
    // r=3
    acc = prod3(ah, al, sXh, sXl, boff);
#pragma unroll
    for (int t = 0; t < 16; t++) T3[t] = 2.f * acc[t] - T1[t];
    __syncthreads(); tstore16(sXh, sXl, bcol, R, half, T3); __syncthreads();
    // r=4
    acc = prod3(ah, al, sXh, sXl, boff);
#pragma unroll
    for (int t = 0; t < 16; t++) T4[t] = 2.f * acc[t] - T2[t];
    __syncthreads(); tstore16(sXh, sXl, bcol, R, half, T4); __syncthreads();
    // r=5
    acc = prod3(ah, al, sXh, sXl, boff);
#pragma unroll
    for (int t = 0; t < 16; t++) T5[t] = 2.f * acc[t] - T3[t];
    __syncthreads(); tstore16(sXh, sXl, bcol, R, half, T5); __syncthreads();
    // r=6
    acc = prod3(ah, al, sXh, sXl, boff);
#pragma unroll
    for (int t = 0; t < 16; t++) T6[t] = 2.f * acc[t] - T4[t];
    __syncthreads(); tstore16(sXh, sXl, bcol, R, half, T6); __syncthreads();
    // r=7 -> Y (only needed as A-operand)
    acc = prod3(ah, al, sXh, sXl, boff);
    f32x16 Y7;
#pragma unroll
    for (int t = 0; t < 16; t++) Y7[t] = 2.f * acc[t] - T5[t];
    __syncthreads(); tstore16(sXh, sXl, bcol, R, half, Y7); __syncthreads();

    load_afrags(sXh, sXl, aoff, ah, al);             // A := Y
    // Clenshaw in Y with matrix coefficients G_q
    f32x16 bq1, bq2;
#pragma unroll
    for (int t = 0; t < 16; t++) {
      bq1[t] = co.a[6][0] * dg[t] + co.a[6][1] * T1[t] + co.a[6][2] * T2[t] + co.a[6][3] * T3[t]
             + co.a[6][4] * T4[t] + co.a[6][5] * T5[t] + co.a[6][6] * T6[t];
      bq2[t] = 0.f;
    }
    __syncthreads();                                  // A-frag reads done before overwrite
    tstore16(sXh, sXl, bcol, R, half, bq1); __syncthreads();

#pragma unroll
    for (int q = 5; q >= 1; q--) {
      acc = prod3(ah, al, sXh, sXl, boff);
      f32x16 nb;
#pragma unroll
      for (int t = 0; t < 16; t++) {
        float gq = co.a[q][0] * dg[t] + co.a[q][1] * T1[t] + co.a[q][2] * T2[t] + co.a[q][3] * T3[t]
                 + co.a[q][4] * T4[t] + co.a[q][5] * T5[t] + co.a[q][6] * T6[t];
        nb[t] = gq + 2.f * acc[t] - bq2[t];
      }
      bq2 = bq1; bq1 = nb;
      __syncthreads(); tstore16(sXh, sXl, bcol, R, half, bq1); __syncthreads();
    }
    acc = prod3(ah, al, sXh, sXl, boff);              // Y*b_1
#pragma unroll
    for (int t = 0; t < 16; t++) {
      float g0 = co.a[0][0] * dg[t] + co.a[0][1] * T1[t] + co.a[0][2] * T2[t] + co.a[0][3] * T3[t]
               + co.a[0][4] * T4[t] + co.a[0][5] * T5[t] + co.a[0][6] * T6[t];
      accTm[t] += g0 + acc[t] - bq2[t];
    }
    __syncthreads();                                  // before next matrix overwrites X
  }

  // write block-partial sum of logs (D-layout scatter; once per block)
  float* pp = partial + (size_t)blockIdx.x * 4096;
#pragma unroll
  for (int g = 0; g < 4; g++)
#pragma unroll
    for (int t = 0; t < 4; t++)
      pp[(32 * R + 8 * g + 4 * half + t) * 64 + bcol] = accTm[4 * g + t];
}

// ---------- single-matrix sqrt/invsqrt via binomial series ----------

__global__ __launch_bounds__(256) void invsqrt_series(const float* __restrict__ Min,
                                                      float* __restrict__ MiOut,
                                                      float* __restrict__ MsOut) {
  __shared__ float sM[4096], sE[4096], sE2[4096], sE3[4096];
  __shared__ float csh;
  const int tid = threadIdx.x;
  const int r0 = (tid >> 4) << 2, c0 = (tid & 15) << 2;

  stage64(Min, sM, tid);
  __syncthreads();
  if (tid == 0) {
    float s = 0.f;
    for (int i = 0; i < 64; i++) s += sM[i * 64 + i];
    csh = s * (1.f / 64.f);
  }
  __syncthreads();
  const float invc = 1.f / csh;
  for (int idx = tid; idx < 4096; idx += 256) {
    int r = idx >> 6, c = idx & 63;
    sE[idx] = 0.5f * (sM[idx] + sM[c * 64 + r]) * invc - ((r == c) ? 1.f : 0.f);
  }
  __syncthreads();

  float t[16];
  gemm_tile_sym(sE, sE, r0, c0, t);  store_tile(sE2, r0, c0, t); __syncthreads();
  gemm_tile_sym(sE2, sE, r0, c0, t); store_tile(sE3, r0, c0, t); __syncthreads();
  gemm_tile_sym(sE2, sE2, r0, c0, t); store_tile(sM, r0, c0, t); __syncthreads();
  float t5[16];
  gemm_tile_sym(sE2, sE3, r0, c0, t5);

  const float sc = sqrtf(csh), rsc = 1.f / sc;
#pragma unroll
  for (int i = 0; i < 4; i++)
#pragma unroll
    for (int j = 0; j < 4; j++) {
      int off = (r0 + i) * 64 + (c0 + j);
      float d = ((r0 + i) == (c0 + j)) ? 1.f : 0.f;
      float e = sE[off], e2 = sE2[off], e3 = sE3[off], e4 = sM[off], e5 = t5[4 * i + j];
      float mi = (d - 0.5f * e + 0.375f * e2 - 0.3125f * e3 + 0.2734375f * e4 - 0.24609375f * e5) * rsc;
      float ms = (d + 0.5f * e - 0.125f * e2 + 0.0625f * e3 - 0.0390625f * e4 + 0.02734375f * e5) * sc;
      MiOut[off] = mi;
      MsOut[off] = ms;
    }
}

// ---------- Taylor-8 expm ----------

__device__ void taylor_expm8(const float* __restrict__ sA, float* __restrict__ sR,
                             int tid, int r0, int c0, float postscale) {
  for (int idx = tid; idx < 4096; idx += 256) {
    int r = idx >> 6, c = idx & 63;
    sR[idx] = ((r == c) ? 1.f : 0.f) + sA[idx] * 0.125f;
  }
  __syncthreads();
  float t[16];
#pragma unroll 1
  for (int k = 7; k >= 1; k--) {
    gemm_tile_sym(sA, sR, r0, c0, t);
    __syncthreads();
    const float inv = 1.f / (float)k;
    const float fin = (k == 1) ? postscale : 1.f;
#pragma unroll
    for (int i = 0; i < 4; i++)
#pragma unroll
      for (int j = 0; j < 4; j++) {
        int off = (r0 + i) * 64 + (c0 + j);
        float d = ((r0 + i) == (c0 + j)) ? 1.f : 0.f;
        sR[off] = (d + t[4 * i + j] * inv) * fin;
      }
    __syncthreads();
  }
}

__global__ __launch_bounds__(256) void expm_update(const float* __restrict__ Tin,
                                                   const float* __restrict__ Msin,
                                                   float* __restrict__ Mout) {
  __shared__ float sA[4096], sR[4096], sB[4096];
  __shared__ float mush;
  const int tid = threadIdx.x;
  const int r0 = (tid >> 4) << 2, c0 = (tid & 15) << 2;

  stage64(Tin, sB, tid);
  __syncthreads();
  if (tid == 0) {
    float s = 0.f;
    for (int i = 0; i < 64; i++) s += sB[i * 64 + i];
    mush = s * (1.f / 64.f);
  }
  __syncthreads();
  const float mu = mush;
  for (int idx = tid; idx < 4096; idx += 256) {
    int r = idx >> 6, c = idx & 63;
    sA[idx] = 0.5f * (sB[idx] + sB[c * 64 + r]) - ((r == c) ? mu : 0.f);
  }
  __syncthreads();
  taylor_expm8(sA, sR, tid, r0, c0, expf(mu));

  stage64(Msin, sB, tid);
  __syncthreads();
  float t[16];
  gemm_tile_sym(sR, sB, r0, c0, t);
  store_tile(sA, r0, c0, t);
  __syncthreads();
  gemm_tile_sym(sB, sA, r0, c0, t);
#pragma unroll
  for (int i = 0; i < 4; i++)
    *(float4*)(Mout + (r0 + i) * 64 + c0) = *(const float4*)(&t[4 * i]);
}

__global__ __launch_bounds__(256) void bias_expm_P(const float* __restrict__ bias,
                                                   const float* __restrict__ Gin,
                                                   float* __restrict__ Pout) {
  __shared__ float sA[4096], sR[4096], sB[4096];
  const int tid = threadIdx.x;
  const int r0 = (tid >> 4) << 2, c0 = (tid & 15) << 2;

  stage64(bias, sB, tid);
  __syncthreads();
  for (int idx = tid; idx < 4096; idx += 256) {
    int r = idx >> 6, c = idx & 63;
    sA[idx] = 0.0625f * (sB[idx] + sB[c * 64 + r]);
  }
  __syncthreads();
  taylor_expm8(sA, sR, tid, r0, c0, 1.f);

  float t[16];
  gemm_tile_sym(sR, sR, r0, c0, t);
  store_tile(sB, r0, c0, t);
  __syncthreads();
  gemm_tile_sym(sB, sB, r0, c0, t);
  store_tile(sR, r0, c0, t);
  stage64(Gin, sA, tid);
  __syncthreads();
  gemm_tile_sym(sR, sA, r0, c0, t);
#pragma unroll
  for (int i = 0; i < 4; i++)
    *(float4*)(Pout + (r0 + i) * 64 + c0) = *(const float4*)(&t[4 * i]);
}

__global__ __launch_bounds__(256) void final_out(const float* __restrict__ data,
                                                 const float* __restrict__ Pin,
                                                 float* __restrict__ out) {
  __shared__ float sPT[4096], sD[4096], sT[4096];
  const int tid = threadIdx.x;
  const int r0 = (tid >> 4) << 2, c0 = (tid & 15) << 2;

  for (int idx = tid; idx < 4096; idx += 256) {
    int r = idx >> 6, c = idx & 63;
    sPT[c * 64 + r] = Pin[idx];
  }
  __syncthreads();
  float t[16];
#pragma unroll 1
  for (int m = 0; m < 8; m++) {
    size_t b = (size_t)blockIdx.x * 8 + m;
    stage64(data + b * 4096, sD, tid);
    __syncthreads();
    gemm_tile_sym(sD, sPT, r0, c0, t);
    store_tile(sT, r0, c0, t);
    __syncthreads();
    gemm_tile_sym(sPT, sT, r0, c0, t);
    float* ob = out + b * 4096;
#pragma unroll
    for (int i = 0; i < 4; i++)
      *(float4*)(ob + (r0 + i) * 64 + c0) = *(const float4*)(&t[4 * i]);
    __syncthreads();
  }
}

// ---------- launch ----------

extern "C" void kernel_launch(void* const* d_in, const int* in_sizes, int n_in,
                              void* d_out, int out_size, void* d_ws, size_t ws_size,
                              hipStream_t stream) {
  const float* data = (const float*)d_in[0];
  const float* bias = (const float*)d_in[1];
  float* out = (float*)d_out;

  float* part = out;                 // 16 MB partial scratch inside d_out
  float* M  = (float*)d_ws;
  float* Mi = M + 4096;
  float* Ms = Mi + 4096;
  float* Tm = Ms + 4096;
  float* G  = Tm + 4096;
  float* P  = G + 4096;

  // Chebyshev coefficients of log on [a,b], then exact Paterson-Stockmeyer
  // re-factoring: sum_k c_k T_k = sum_q [sum_r a_qr T_r] T_q(T_s), s=7, Q=6.
  PSArg co;
  {
    const double a = A_CHEB, b = B_CHEB;
    const int N = 256;
    double c[64] = {0};
    for (int j = 0; j <= K_CHEB; j++) {
      double s = 0.0;
      for (int k = 0; k < N; k++) {
        double th = M_PI * (k + 0.5) / N;
        double x = 0.5 * (a + b) + 0.5 * (b - a) * std::cos(th);
        s += std::log(x) * std::cos(j * th);
      }
      c[j] = 2.0 * s / N;
    }
    c[0] *= 0.5;                     // plain sum convention
    double aa[PS_Q + 1][PS_S] = {};
    for (int q = PS_Q; q >= 1; --q) {
      for (int r = PS_S - 1; r >= 1; --r) {
        int k = q * PS_S + r;
        double av = 2.0 * c[k];
        aa[q][r] = av;
        c[k] -= av * 0.5;            // -> 0
        c[q * PS_S - r] -= av * 0.5; // reflection T_r*T_qs = (T_qs+r + T_qs-r)/2
      }
      aa[q][0] = c[q * PS_S];
      c[q * PS_S] = 0.0;
    }
    for (int r = 0; r < PS_S; r++) aa[0][r] = c[r];
    co.mid = (float)(0.5 * (a + b));
    co.invhalf = (float)(2.0 / (b - a));
    for (int q = 0; q <= PS_Q; q++)
      for (int r = 0; r < PS_S; r++) co.a[q][r] = (float)aa[q][r];
  }

  reduce_mean8<<<1024, 256, 0, stream>>>(data, part);
  reduce_cols<<<16, 256, 0, stream>>>(part, M, 1024, 1.f / 8192.f);

  for (int it = 0; it < 3; ++it) {
    invsqrt_series<<<1, 256, 0, stream>>>(M, Mi, Ms);
    cheb_ps<<<1024, 256, 0, stream>>>(data, Mi, part, co);
    reduce_cols<<<16, 256, 0, stream>>>(part, Tm, 1024, 1.f / 8192.f);
    expm_update<<<1, 256, 0, stream>>>(Tm, Ms, M);
  }

  invsqrt_series<<<1, 256, 0, stream>>>(M, G, Ms);
  bias_expm_P<<<1, 256, 0, stream>>>(bias, G, P);
  final_out<<<1024, 256, 0, stream>>>(data, P, out);
}